// Round 1
// baseline (213.913 us; speedup 1.0000x reference)
//
#include <hip/hip_runtime.h>
#include <cmath>

#define NDEV   100000
#define NBATCH 8192
#define CONTF  62
#define EMB    16
#define FEAT   94      // 62 + 16 + 16
#define KNBR   64
#define NH     4
#define OUTD   16
#define HOUT   64      // NH*OUTD
#define FUS    204     // 94 + 94 + 16
#define ALPHA  0.2f

// ---------------- workspace layout (floats) ----------------
// h_d    : NDEV*64      = 6,400,000   @ 0
// e_d    : NDEV*4       =   400,000   @ 6,400,000
// combws : NBATCH*94    =   770,048   @ 6,800,000
// e_c    : NBATCH*4     =    32,768   @ 7,570,048
// fus8   : NBATCH*204   = 1,671,168   @ 7,602,816   (8-row interleaved)
// total ≈ 9.28M floats ≈ 37.1 MB

__device__ __forceinline__ float ld_feat(const float* __restrict__ c,
                                         const float* __restrict__ e0,
                                         const float* __restrict__ e1, int f) {
  return (f < CONTF) ? c[f] : (f < CONTF + EMB) ? e0[f - CONTF] : e1[f - CONTF - EMB];
}

// 94-length dot with 4 accumulators (breaks FMA latency chain)
__device__ __forceinline__ float dot94(const float* __restrict__ c,
                                       const float* __restrict__ e0,
                                       const float* __restrict__ e1,
                                       const float* w, float bias) {
  float a0 = bias, a1 = 0.f, a2 = 0.f, a3 = 0.f;
#pragma unroll
  for (int f = 0; f < 92; f += 4) {
    a0 = fmaf(ld_feat(c, e0, e1, f + 0), w[f + 0], a0);
    a1 = fmaf(ld_feat(c, e0, e1, f + 1), w[f + 1], a1);
    a2 = fmaf(ld_feat(c, e0, e1, f + 2), w[f + 2], a2);
    a3 = fmaf(ld_feat(c, e0, e1, f + 3), w[f + 3], a3);
  }
  a0 = fmaf(ld_feat(c, e0, e1, 92), w[92], a0);
  a1 = fmaf(ld_feat(c, e0, e1, 93), w[93], a1);
  return (a0 + a1) + (a2 + a3);
}

// ---------------- K1: per-device h_d + e_d ----------------
__global__ __launch_bounds__(256, 2) void k_dev(
    const float* __restrict__ device_cont, const int* __restrict__ device_cat,
    const float* __restrict__ de0, const float* __restrict__ de1,
    const float* __restrict__ Wd, const float* __restrict__ bd,
    const float* __restrict__ aW,
    float* __restrict__ h_d, float* __restrict__ e_d) {
  const int lane = threadIdx.x & 63;
  const int wid  = __builtin_amdgcn_readfirstlane((int)(threadIdx.x >> 6));
  const int h = lane >> 4, o = lane & 15;
  const int nw = gridDim.x * 4;

  float w[FEAT];
#pragma unroll
  for (int f = 0; f < FEAT; ++f) w[f] = Wd[(h * FEAT + f) * OUTD + o];
  const float bias = bd[lane];
  const float a2l  = aW[h * 32 + 16 + o];

  for (int d = blockIdx.x * 4 + wid; d < NDEV; d += nw) {
    const float* crow = device_cont + (size_t)d * CONTF;
    const int c0 = device_cat[2 * d], c1 = device_cat[2 * d + 1];
    const float* e0 = de0 + c0 * EMB;
    const float* e1 = de1 + c1 * EMB;
    const float acc = dot94(crow, e0, e1, w, bias);
    h_d[(size_t)d * HOUT + lane] = acc;
    float part = acc * a2l;
    part += __shfl_xor(part, 1);
    part += __shfl_xor(part, 2);
    part += __shfl_xor(part, 4);
    part += __shfl_xor(part, 8);
    if (o == 0) e_d[(size_t)d * NH + h] = part;
  }
}

// ---------------- K2: per-row comb_batch + e_c ----------------
__global__ __launch_bounds__(256, 2) void k_comb(
    const float* __restrict__ combin_cont, const int* __restrict__ combin_cat,
    const int* __restrict__ combin_idx,
    const float* __restrict__ ce0, const float* __restrict__ ce1,
    const float* __restrict__ Wc, const float* __restrict__ bc,
    const float* __restrict__ aW,
    float* __restrict__ combws, float* __restrict__ e_c) {
  const int lane = threadIdx.x & 63;
  const int wid  = __builtin_amdgcn_readfirstlane((int)(threadIdx.x >> 6));
  const int h = lane >> 4, o = lane & 15;
  const int nw = gridDim.x * 4;

  float w[FEAT];
#pragma unroll
  for (int f = 0; f < FEAT; ++f) w[f] = Wc[(h * FEAT + f) * OUTD + o];
  const float bias = bc[lane];
  const float a1l  = aW[h * 32 + o];

  for (int b = blockIdx.x * 4 + wid; b < NBATCH; b += nw) {
    const int ci = combin_idx[b];
    const float* crow = combin_cont + (size_t)ci * CONTF;
    const int c0 = combin_cat[2 * ci], c1 = combin_cat[2 * ci + 1];
    const float* e0 = ce0 + c0 * EMB;
    const float* e1 = ce1 + c1 * EMB;
    const float acc = dot94(crow, e0, e1, w, bias);
    float part = acc * a1l;
    part += __shfl_xor(part, 1);
    part += __shfl_xor(part, 2);
    part += __shfl_xor(part, 4);
    part += __shfl_xor(part, 8);
    if (o == 0) e_c[(size_t)b * NH + h] = part;
    // materialize comb_batch row (94 floats), lane-distributed
    {
      const int i = lane;  // 0..63 always < 94
      float v = (i < CONTF) ? crow[i] : (i < CONTF + EMB) ? e0[i - CONTF] : e1[i - CONTF - EMB];
      combws[(size_t)b * FEAT + i] = v;
      const int i2 = lane + 64;  // 64..127, >62 so always embedding range
      if (i2 < FEAT) {
        float v2 = (i2 < CONTF + EMB) ? e0[i2 - CONTF] : e1[i2 - CONTF - EMB];
        combws[(size_t)b * FEAT + i2] = v2;
      }
    }
  }
}

// ---------------- K3: attention + fusion-row build ----------------
__global__ __launch_bounds__(256, 4) void k_attn(
    const int* __restrict__ neighbor_idx, const int* __restrict__ device_idx,
    const int* __restrict__ device_cat, const float* __restrict__ device_cont,
    const float* __restrict__ de0, const float* __restrict__ de1,
    const float* __restrict__ h_d, const float* __restrict__ e_d,
    const float* __restrict__ e_c, const float* __restrict__ ab,
    const float* __restrict__ W1, const float* __restrict__ b1,
    const float* __restrict__ combws, float* __restrict__ fus8) {
  __shared__ __align__(16) float pb[4][NH][68];  // 68: bank-spread padding
  __shared__ __align__(16) int   nb[4][KNBR];
  __shared__ float hb[4][HOUT];
  __shared__ float afb[4][OUTD];

  const int lane = threadIdx.x & 63;
  const int wid  = __builtin_amdgcn_readfirstlane((int)(threadIdx.x >> 6));
  const int b    = blockIdx.x * 4 + wid;

  // ---- phase 1: lane = neighbor k ----
  const int nk = neighbor_idx[(size_t)b * KNBR + lane];
  const float4 ed4 = *reinterpret_cast<const float4*>(e_d + (size_t)nk * NH);
  const float4 ec4 = *reinterpret_cast<const float4*>(e_c + (size_t)b * NH);
  const float4 ab4 = *reinterpret_cast<const float4*>(ab);

  float v0 = ec4.x + ed4.x + ab4.x;
  float v1 = ec4.y + ed4.y + ab4.y;
  float v2 = ec4.z + ed4.z + ab4.z;
  float v3 = ec4.w + ed4.w + ab4.w;
  v0 = v0 > 0.f ? v0 : ALPHA * v0;
  v1 = v1 > 0.f ? v1 : ALPHA * v1;
  v2 = v2 > 0.f ? v2 : ALPHA * v2;
  v3 = v3 > 0.f ? v3 : ALPHA * v3;

  float m0 = v0, m1 = v1, m2 = v2, m3 = v3;
#pragma unroll
  for (int msk = 1; msk < 64; msk <<= 1) {
    m0 = fmaxf(m0, __shfl_xor(m0, msk));
    m1 = fmaxf(m1, __shfl_xor(m1, msk));
    m2 = fmaxf(m2, __shfl_xor(m2, msk));
    m3 = fmaxf(m3, __shfl_xor(m3, msk));
  }
  float p0 = expf(v0 - m0), p1 = expf(v1 - m1), p2 = expf(v2 - m2), p3 = expf(v3 - m3);
  float s0 = p0, s1 = p1, s2 = p2, s3 = p3;
#pragma unroll
  for (int msk = 1; msk < 64; msk <<= 1) {
    s0 += __shfl_xor(s0, msk);
    s1 += __shfl_xor(s1, msk);
    s2 += __shfl_xor(s2, msk);
    s3 += __shfl_xor(s3, msk);
  }
  p0 /= s0; p1 /= s1; p2 /= s2; p3 /= s3;

  pb[wid][0][lane] = p0;
  pb[wid][1][lane] = p1;
  pb[wid][2][lane] = p2;
  pb[wid][3][lane] = p3;
  nb[wid][lane]    = nk;
  __syncthreads();

  // ---- phase 2: lane = (h,o) ----
  const int h = lane >> 4;  // head
  float acc = 0.f;
#pragma unroll
  for (int j = 0; j < 16; ++j) {
    const float4 p4 = *reinterpret_cast<const float4*>(&pb[wid][h][4 * j]);
    const int4   n4 = *reinterpret_cast<const int4*>(&nb[wid][4 * j]);
    acc = fmaf(p4.x, h_d[(size_t)n4.x * HOUT + lane], acc);
    acc = fmaf(p4.y, h_d[(size_t)n4.y * HOUT + lane], acc);
    acc = fmaf(p4.z, h_d[(size_t)n4.z * HOUT + lane], acc);
    acc = fmaf(p4.w, h_d[(size_t)n4.w * HOUT + lane], acc);
  }
  const float ho = acc > 0.f ? acc : expm1f(acc);  // elu
  hb[wid][lane] = ho;
  __syncthreads();

  // ---- attn_feats = head_out(64) @ W1(64x16) + b1 ----
  {
    const int j = lane & 15, g = lane >> 4;
    float part = 0.f;
#pragma unroll
    for (int t = 0; t < 16; ++t)
      part = fmaf(hb[wid][g * 16 + t], W1[(g * 16 + t) * OUTD + j], part);
    part += __shfl_xor(part, 16);
    part += __shfl_xor(part, 32);
    if (lane < 16) afb[wid][lane] = part + b1[lane];
  }
  __syncthreads();

  // ---- write fusion row: [comb 94 | dev 94 | att 16] in 8-row-interleaved layout ----
  const int didx = device_idx[b];
  const int dc0 = device_cat[2 * didx], dc1 = device_cat[2 * didx + 1];
  float* base = fus8 + (size_t)(b >> 3) * (FUS * 8) + (b & 7);
#pragma unroll
  for (int t = 0; t < 4; ++t) {
    const int i = lane + t * 64;
    if (i < FUS) {
      float v;
      if (i < 94)       v = combws[(size_t)b * FEAT + i];
      else if (i < 156) v = device_cont[(size_t)didx * CONTF + (i - 94)];
      else if (i < 172) v = de0[dc0 * EMB + (i - 156)];
      else if (i < 188) v = de1[dc1 * EMB + (i - 172)];
      else              v = afb[wid][i - 188];
      base[(size_t)i * 8] = v;
    }
  }
}

// ---------------- K4: MLP (fusion 204 -> 64 -> 32 -> 1) ----------------
__global__ __launch_bounds__(256, 2) void k_mlp(
    const float* __restrict__ fus8,
    const float* __restrict__ W2, const float* __restrict__ b2,
    const float* __restrict__ W3, const float* __restrict__ b3,
    const float* __restrict__ W4, const float* __restrict__ b4,
    float* __restrict__ out) {
  __shared__ __align__(16) float x1b[4][8][64];
  const int lane = threadIdx.x & 63;
  const int wid  = __builtin_amdgcn_readfirstlane((int)(threadIdx.x >> 6));
  const int g    = blockIdx.x * 4 + wid;  // row-group of 8
  const float* fg = fus8 + (size_t)g * (FUS * 8);

  float acc[8];
  const float bj = b2[lane];
#pragma unroll
  for (int r = 0; r < 8; ++r) acc[r] = bj;

#pragma unroll 4
  for (int i = 0; i < FUS; ++i) {
    const float wv = W2[i * 64 + lane];       // lane = x1 column
    const float* fr = fg + i * 8;             // wave-uniform -> s_load
#pragma unroll
    for (int r = 0; r < 8; ++r) acc[r] = fmaf(fr[r], wv, acc[r]);
  }
#pragma unroll
  for (int r = 0; r < 8; ++r) x1b[wid][r][lane] = fmaxf(acc[r], 0.f);
  __syncthreads();

  const int m = lane & 31, rh = lane >> 5;    // rh picks rows 0-3 / 4-7
  float x2[4];
#pragma unroll
  for (int r = 0; r < 4; ++r) x2[r] = b3[m];
#pragma unroll 4
  for (int j4 = 0; j4 < 16; ++j4) {
    float w30 = W3[(4 * j4 + 0) * 32 + m];
    float w31 = W3[(4 * j4 + 1) * 32 + m];
    float w32 = W3[(4 * j4 + 2) * 32 + m];
    float w33 = W3[(4 * j4 + 3) * 32 + m];
#pragma unroll
    for (int r = 0; r < 4; ++r) {
      const float4 xv = *reinterpret_cast<const float4*>(&x1b[wid][rh * 4 + r][4 * j4]);
      x2[r] = fmaf(xv.x, w30, x2[r]);
      x2[r] = fmaf(xv.y, w31, x2[r]);
      x2[r] = fmaf(xv.z, w32, x2[r]);
      x2[r] = fmaf(xv.w, w33, x2[r]);
    }
  }
  const float w4 = W4[m];
  float part[4];
#pragma unroll
  for (int r = 0; r < 4; ++r) part[r] = fmaxf(x2[r], 0.f) * w4;
#pragma unroll
  for (int msk = 1; msk < 32; msk <<= 1) {
#pragma unroll
    for (int r = 0; r < 4; ++r) part[r] += __shfl_xor(part[r], msk);
  }
  if (m == 0) {
    const float bb = b4[0];
#pragma unroll
    for (int r = 0; r < 4; ++r) {
      const float z = part[r] + bb;
      out[(size_t)g * 8 + rh * 4 + r] = 1.f / (1.f + expf(-z));
    }
  }
}

extern "C" void kernel_launch(void* const* d_in, const int* in_sizes, int n_in,
                              void* d_out, int out_size, void* d_ws, size_t ws_size,
                              hipStream_t stream) {
  const float* combin_cont  = (const float*)d_in[0];
  const int*   combin_cat   = (const int*)d_in[1];
  const float* device_cont  = (const float*)d_in[2];
  const int*   device_cat   = (const int*)d_in[3];
  const int*   combin_idx   = (const int*)d_in[4];
  const int*   device_idx   = (const int*)d_in[5];
  const int*   neighbor_idx = (const int*)d_in[6];
  const float* ce0 = (const float*)d_in[7];
  const float* ce1 = (const float*)d_in[8];
  const float* de0 = (const float*)d_in[9];
  const float* de1 = (const float*)d_in[10];
  const float* Wc  = (const float*)d_in[11];
  const float* bc  = (const float*)d_in[12];
  const float* Wd  = (const float*)d_in[13];
  const float* bd  = (const float*)d_in[14];
  const float* aW  = (const float*)d_in[15];
  const float* ab  = (const float*)d_in[16];
  const float* W1  = (const float*)d_in[17];
  const float* b1  = (const float*)d_in[18];
  const float* W2  = (const float*)d_in[19];
  const float* b2  = (const float*)d_in[20];
  const float* W3  = (const float*)d_in[21];
  const float* b3  = (const float*)d_in[22];
  const float* W4  = (const float*)d_in[23];
  const float* b4  = (const float*)d_in[24];

  float* ws     = (float*)d_ws;
  float* h_d    = ws;
  float* e_d    = ws + 6400000;
  float* combws = ws + 6800000;
  float* e_c    = ws + 7570048;
  float* fus8   = ws + 7602816;

  k_dev<<<1024, 256, 0, stream>>>(device_cont, device_cat, de0, de1, Wd, bd, aW, h_d, e_d);
  k_comb<<<512, 256, 0, stream>>>(combin_cont, combin_cat, combin_idx, ce0, ce1, Wc, bc, aW,
                                  combws, e_c);
  k_attn<<<2048, 256, 0, stream>>>(neighbor_idx, device_idx, device_cat, device_cont, de0, de1,
                                   h_d, e_d, e_c, ab, W1, b1, combws, fus8);
  k_mlp<<<256, 256, 0, stream>>>(fus8, W2, b2, W3, b3, W4, b4, (float*)d_out);
}